// Round 3
// baseline (143.756 us; speedup 1.0000x reference)
//
#include <hip/hip_runtime.h>
#include <stdint.h>

#define NN 15000
#define NE 60000

typedef unsigned short u16;
typedef __attribute__((ext_vector_type(8))) short short8;
typedef __attribute__((ext_vector_type(4))) float f32x4;

// workspace layout (bytes)
#define XF_OFF    0u
#define H_OFF     1920000u      // xf: 15000*64*2
#define W2T_OFF   9600000u      // h : 60000*64*2
#define ROOTT_OFF 10132480u     // w2t: 65*4096*2
#define WCATT_OFF 10140672u     // rootT: 64*64*2
#define SUMS_OFF  10171392u     // wcatT: 240*64*2 ; sums+cnt: 15000*65*4

__device__ __forceinline__ float b2f(u16 u) {
    union { unsigned i; float f; } v; v.i = ((unsigned)u) << 16; return v.f;
}
__device__ __forceinline__ unsigned cvtpk(float lo, float hi) {
    unsigned r;
    asm("v_cvt_pk_bf16_f32 %0, %1, %2" : "=v"(r) : "v"(lo), "v"(hi));
    return r;
}
__device__ __forceinline__ u16 f2b(float f) { return (u16)(cvtpk(f, f) & 0xffffu); }

// ---------------- kernel Z: zero sums+cnt ----------------
__global__ __launch_bounds__(256) void k_zero(float4* __restrict__ p, int n4) {
    int i = blockIdx.x * 256 + threadIdx.x;
    if (i < n4) p[i] = make_float4(0.f, 0.f, 0.f, 0.f);
}

// ---------------- kernel A: xf = bf16(concat(x, in_emb[inp], out_emb[outp])) ----------------
__global__ __launch_bounds__(256) void k_xf(const float* __restrict__ x,
                                            const int* __restrict__ inp,
                                            const int* __restrict__ outp,
                                            const float* __restrict__ in_emb,
                                            const float* __restrict__ out_emb,
                                            u16* __restrict__ xf) {
    int tid = blockIdx.x * 256 + threadIdx.x;
    int n = tid >> 6, j = tid & 63;
    if (n >= NN) return;
    float v;
    if (j < 32)      v = x[n * 32 + j];
    else if (j < 48) v = in_emb[inp[n] * 16 + (j - 32)];
    else             v = out_emb[outp[n] * 16 + (j - 48)];
    xf[n * 64 + j] = f2b(v);
}

// ---------------- kernel T: weight re-layouts (f32 -> bf16) ----------------
// w2t[k][o][i] = w2[k][i*64+o] (k<64); w2t[64][o][i] = b2[i*64+o]
// rootT[c][i] = root_w[i][c];  wcatT[col][k] = Wcat[k][col]
__global__ __launch_bounds__(256) void k_prep(const float* __restrict__ w2,
                                              const float* __restrict__ b2,
                                              const float* __restrict__ rootw,
                                              const float* __restrict__ wsup,
                                              const float* __restrict__ wnt,
                                              const float* __restrict__ wtg,
                                              const float* __restrict__ wpr,
                                              u16* __restrict__ w2t,
                                              u16* __restrict__ rootT,
                                              u16* __restrict__ wcatT) {
    int idx = blockIdx.x * 256 + threadIdx.x;
    if (idx < 65 * 4096) {
        int k = idx >> 12, r = idx & 4095, o = r >> 6, i = r & 63;
        float v = (k < 64) ? w2[(k << 12) + (i << 6) + o] : b2[(i << 6) + o];
        w2t[idx] = f2b(v);
    } else if (idx < 65 * 4096 + 4096) {
        int t = idx - 65 * 4096; int c = t >> 6, i = t & 63;
        rootT[t] = f2b(rootw[i * 64 + c]);
    } else if (idx < 65 * 4096 + 4096 + 15360) {
        int t = idx - (65 * 4096 + 4096); int col = t >> 6, k = t & 63;
        float v;
        if (col < 16)       v = wsup[k * 16 + col];
        else if (col < 48)  v = wnt[k * 32 + col - 16];
        else if (col < 112) v = wtg[k * 64 + col - 48];
        else                v = wpr[k * 128 + col - 112];
        wcatT[t] = f2b(v);
    }
}

// ---------------- kernel B: h = bf16(relu(ea @ w1 + b1)); also degree count ----------------
__global__ __launch_bounds__(256) void k_h(const int* __restrict__ ei,
                                           const int* __restrict__ ent,
                                           const int* __restrict__ enp,
                                           const float* __restrict__ esc,
                                           const float* __restrict__ nt_emb,
                                           const float* __restrict__ np_emb,
                                           const float* __restrict__ w1,
                                           const float* __restrict__ b1,
                                           u16* __restrict__ h,
                                           float* __restrict__ cnt) {
    __shared__ float w1f[33 * 64];
    __shared__ float b1f[64];
    __shared__ float ea[4][34];
    int tid = threadIdx.x;
    for (int i = tid; i < 33 * 64; i += 256) w1f[i] = w1[i];
    if (tid < 64) b1f[tid] = b1[tid];
    int le = tid >> 6, c = tid & 63;
    int e = blockIdx.x * 4 + le;      // NE divisible by 4, grid exact
    if (c < 16)      ea[le][c] = nt_emb[ent[e] * 16 + c];
    else if (c < 32) ea[le][c] = np_emb[enp[e] * 16 + (c - 16)];
    else if (c == 32) ea[le][32] = esc[e];
    __syncthreads();
    float acc = b1f[c];
    #pragma unroll
    for (int i = 0; i < 33; ++i) acc += ea[le][i] * w1f[i * 64 + c];
    acc = fmaxf(acc, 0.0f);
    h[(size_t)e * 64 + c] = f2b(acc);
    if (c == 0) atomicAdd(&cnt[ei[NE + e]], 1.0f);
}

// ---------------- kernel C: fused msg GEMM + scatter-add ----------------
// msg[e,o] = sum_{k,i} (h[e,k]*g[e,i]) * w2t[k][o][i], g = xf[src[e]]
// block: 256 edges, 8 waves. wave = grp(2, k-halves) x qtr(4, 64-edge quads).
// Single-buffered w2t staging, two barriers per K-slice (correctness-first).
__global__ __launch_bounds__(512) void k_msg(const int* __restrict__ ei,
                                             const u16* __restrict__ xf,
                                             const u16* __restrict__ hg,
                                             const u16* __restrict__ w2t,
                                             float* __restrict__ sums) {
    __shared__ __align__(16) char smem[49152];  // [0,32768): h tile (swz); [32768,49152): w2t [2][8192B]
    const int tid  = threadIdx.x;
    const int lane = tid & 63;
    const int wave = tid >> 6;
    const int grp  = wave >> 2;
    const int qtr  = wave & 3;
    const int lhi  = lane >> 4;
    const int llo  = lane & 15;
    const int e0   = blockIdx.x * 256;

    // stage h tile [256][64] bf16, XOR-swizzled (row stride 128B)
    #pragma unroll
    for (int it = 0; it < 4; ++it) {
        int seg = tid + it * 512;
        int row = seg >> 3, part = seg & 7;
        int e = e0 + row;
        uint4 v = make_uint4(0, 0, 0, 0);
        if (e < NE) v = *(const uint4*)(hg + (size_t)e * 64 + part * 8);
        int lin = row * 128 + part * 16;
        *(uint4*)(smem + (lin ^ ((row & 7) << 4))) = v;
    }

    // g fragments (f32) in registers: gf[strip][i-chunk][8]
    float gf[4][2][8];
    #pragma unroll
    for (int st = 0; st < 4; ++st) {
        int e = e0 + qtr * 64 + st * 16 + llo;
        int s = (e < NE) ? ei[e] : 0;
        #pragma unroll
        for (int c = 0; c < 2; ++c) {
            uint4 raw = make_uint4(0, 0, 0, 0);
            if (e < NE) raw = *(const uint4*)(xf + (size_t)s * 64 + c * 32 + lhi * 8);
            unsigned u[4] = {raw.x, raw.y, raw.z, raw.w};
            #pragma unroll
            for (int p = 0; p < 4; ++p) {
                union { unsigned i; float f; } lo, hi;
                lo.i = u[p] << 16; hi.i = u[p] & 0xffff0000u;
                gf[st][c][2 * p] = lo.f; gf[st][c][2 * p + 1] = hi.f;
            }
        }
    }

    f32x4 acc[4][4];
    #pragma unroll
    for (int st = 0; st < 4; ++st)
        #pragma unroll
        for (int o = 0; o < 4; ++o)
            acc[st][o] = (f32x4){0.f, 0.f, 0.f, 0.f};

    for (int s = 0; s < 33; ++s) {
        const int sl0 = (s < 32) ? s : 64;          // grp0 slice schedule (64 = bias slice)
        const int sl1 = (s < 32) ? (32 + s) : 64;   // grp1 (s=32 unused dummy)
        uint4 v0 = *(const uint4*)((const char*)w2t + (size_t)sl0 * 8192 + tid * 16);
        uint4 v1 = *(const uint4*)((const char*)w2t + (size_t)sl1 * 8192 + tid * 16);
        __syncthreads();   // prior iteration's reads (and s=0: h staging) complete
        {
            int lin = tid * 16;
            int phys = lin ^ (((lin >> 7) & 7) << 4);
            *(uint4*)(smem + 32768 + phys) = v0;
            *(uint4*)(smem + 32768 + 8192 + phys) = v1;
        }
        __syncthreads();   // staged slice visible

        const char* wbase = smem + 32768 + grp * 8192;
        short8 bfr[2][4];
        #pragma unroll
        for (int c = 0; c < 2; ++c)
            #pragma unroll
            for (int o = 0; o < 4; ++o) {
                int loff = (o * 16 + llo) * 128 + c * 64 + lhi * 16;
                int phys = loff ^ ((llo & 7) << 4);
                bfr[c][o] = *(const short8*)(wbase + phys);
            }
        if (grp == 0 || s < 32) {
            const bool bias = (grp == 0 && s == 32);
            const int k = (grp == 0) ? s : (32 + s);
            #pragma unroll
            for (int st = 0; st < 4; ++st) {
                float hf = 1.0f;
                if (!bias) {
                    int erow = qtr * 64 + st * 16 + llo;
                    int hoff = (erow * 128 + k * 2) ^ ((erow & 7) << 4);
                    hf = b2f(*(const u16*)(smem + hoff));
                }
                short8 a[2];
                #pragma unroll
                for (int c = 0; c < 2; ++c) {
                    union { short8 s8; unsigned u[4]; } A;
                    #pragma unroll
                    for (int p = 0; p < 4; ++p)
                        A.u[p] = cvtpk(hf * gf[st][c][2 * p], hf * gf[st][c][2 * p + 1]);
                    a[c] = A.s8;
                }
                #pragma unroll
                for (int c = 0; c < 2; ++c)
                    #pragma unroll
                    for (int o = 0; o < 4; ++o)
                        acc[st][o] = __builtin_amdgcn_mfma_f32_16x16x32_bf16(
                            a[c], bfr[c][o], acc[st][o], 0, 0, 0);
            }
        }
    }

    // scatter-add into sums[dst]: C/D layout col=lane&15, row=(lane>>4)*4+r
    #pragma unroll
    for (int st = 0; st < 4; ++st) {
        #pragma unroll
        for (int r = 0; r < 4; ++r) {
            int e = e0 + qtr * 64 + st * 16 + lhi * 4 + r;
            if (e < NE) {
                int d = ei[NE + e];
                float* base = sums + (size_t)d * 64;
                #pragma unroll
                for (int o = 0; o < 4; ++o)
                    atomicAdd(base + o * 16 + llo, acc[st][o][r]);
            }
        }
    }
}

// ---------------- kernel D: out = relu(aggr + xf@rootw + b); 4 heads (f32 out) ----------------
__global__ __launch_bounds__(256) void k_out(const u16* __restrict__ xf,
                                             const float* __restrict__ sums,
                                             const float* __restrict__ cnt,
                                             const u16* __restrict__ rootT,
                                             const u16* __restrict__ wcatT,
                                             const float* __restrict__ convb,
                                             const float* __restrict__ bsup,
                                             const float* __restrict__ bnt,
                                             const float* __restrict__ btg,
                                             const float* __restrict__ bpr,
                                             float* __restrict__ outp) {
    __shared__ __align__(16) u16 outlds[4][16][72];
    int tid = threadIdx.x;
    int wave = tid >> 6, lane = tid & 63;
    int lhi = lane >> 4, llo = lane & 15;
    int sid = blockIdx.x * 4 + wave;
    const bool live = (sid < 938);        // 938 = ceil(15000/16)
    if (!live) sid = 937;                 // clamp; keep all threads for barrier
    int n0 = sid * 16;

    short8 a1[2];
    #pragma unroll
    for (int c = 0; c < 2; ++c) {
        int node = n0 + llo; if (node >= NN) node = NN - 1;
        a1[c] = *(const short8*)(xf + (size_t)node * 64 + c * 32 + lhi * 8);
    }
    f32x4 racc[4];
    #pragma unroll
    for (int o = 0; o < 4; ++o) racc[o] = (f32x4){0.f, 0.f, 0.f, 0.f};
    #pragma unroll
    for (int c = 0; c < 2; ++c)
        #pragma unroll
        for (int o = 0; o < 4; ++o) {
            short8 b = *(const short8*)(rootT + (o * 16 + llo) * 64 + c * 32 + lhi * 8);
            racc[o] = __builtin_amdgcn_mfma_f32_16x16x32_bf16(a1[c], b, racc[o], 0, 0, 0);
        }
    #pragma unroll
    for (int o = 0; o < 4; ++o) {
        int col = o * 16 + llo;
        #pragma unroll
        for (int r = 0; r < 4; ++r) {
            int node = n0 + lhi * 4 + r;
            float v = 0.f;
            if (node < NN) v = sums[(size_t)node * 64 + col] / fmaxf(cnt[node], 1.0f);
            v += racc[o][r] + convb[col];
            v = fmaxf(v, 0.f);
            outlds[wave][lhi * 4 + r][col] = f2b(v);
        }
    }
    __syncthreads();
    short8 a2[2];
    #pragma unroll
    for (int c = 0; c < 2; ++c)
        a2[c] = *(const short8*)(&outlds[wave][llo][c * 32 + lhi * 8]);
    #pragma unroll
    for (int o = 0; o < 15; ++o) {
        f32x4 hacc = (f32x4){0.f, 0.f, 0.f, 0.f};
        #pragma unroll
        for (int c = 0; c < 2; ++c) {
            short8 b = *(const short8*)(wcatT + (o * 16 + llo) * 64 + c * 32 + lhi * 8);
            hacc = __builtin_amdgcn_mfma_f32_16x16x32_bf16(a2[c], b, hacc, 0, 0, 0);
        }
        int col = o * 16 + llo;
        float bv; size_t off0; int w_, csh;
        if (col < 16)       { bv = bsup[col];       off0 = 0;                 w_ = 16;  csh = 0;   }
        else if (col < 48)  { bv = bnt[col - 16];   off0 = (size_t)NN * 16;   w_ = 32;  csh = 16;  }
        else if (col < 112) { bv = btg[col - 48];   off0 = (size_t)NN * 48;   w_ = 64;  csh = 48;  }
        else                { bv = bpr[col - 112];  off0 = (size_t)NN * 112;  w_ = 128; csh = 112; }
        #pragma unroll
        for (int r = 0; r < 4; ++r) {
            int node = n0 + lhi * 4 + r;
            if (live && node < NN)
                outp[off0 + (size_t)node * w_ + (col - csh)] = hacc[r] + bv;
        }
    }
}

extern "C" void kernel_launch(void* const* d_in, const int* in_sizes, int n_in,
                              void* d_out, int out_size, void* d_ws, size_t ws_size,
                              hipStream_t stream) {
    const float* x        = (const float*)d_in[0];
    const int* input_np   = (const int*)d_in[1];
    const int* output_np  = (const int*)d_in[2];
    const int* edge_idx   = (const int*)d_in[3];
    const int* edge_nt    = (const int*)d_in[4];
    const int* edge_np    = (const int*)d_in[5];
    const float* edge_sc  = (const float*)d_in[6];
    const float* in_emb   = (const float*)d_in[7];
    const float* out_emb  = (const float*)d_in[8];
    const float* enp_emb  = (const float*)d_in[9];
    const float* ent_emb  = (const float*)d_in[10];
    const float* w1       = (const float*)d_in[11];
    const float* b1       = (const float*)d_in[12];
    const float* w2       = (const float*)d_in[13];
    const float* b2       = (const float*)d_in[14];
    const float* rootw    = (const float*)d_in[15];
    const float* convb    = (const float*)d_in[16];
    const float* wsup     = (const float*)d_in[17];
    const float* bsup     = (const float*)d_in[18];
    const float* wnt      = (const float*)d_in[19];
    const float* bnt      = (const float*)d_in[20];
    const float* wtg      = (const float*)d_in[21];
    const float* btg      = (const float*)d_in[22];
    const float* wpr      = (const float*)d_in[23];
    const float* bpr      = (const float*)d_in[24];

    char* ws = (char*)d_ws;
    u16* xf    = (u16*)(ws + XF_OFF);
    u16* hbuf  = (u16*)(ws + H_OFF);
    u16* w2t   = (u16*)(ws + W2T_OFF);
    u16* rootT = (u16*)(ws + ROOTT_OFF);
    u16* wcatT = (u16*)(ws + WCATT_OFF);
    float* sums = (float*)(ws + SUMS_OFF);
    float* cnt  = sums + (size_t)NN * 64;

    k_zero<<<953, 256, 0, stream>>>((float4*)sums, (NN * 65) / 4);
    k_prep<<<1116, 256, 0, stream>>>(w2, b2, rootw, wsup, wnt, wtg, wpr, w2t, rootT, wcatT);
    k_xf<<<3750, 256, 0, stream>>>(x, input_np, output_np, in_emb, out_emb, xf);
    k_h<<<15000, 256, 0, stream>>>(edge_idx, edge_nt, edge_np, edge_sc, ent_emb, enp_emb, w1, b1, hbuf, cnt);
    k_msg<<<235, 512, 0, stream>>>(edge_idx, xf, hbuf, w2t, sums);
    k_out<<<235, 256, 0, stream>>>(xf, sums, cnt, rootT, wcatT, convb, bsup, bnt, btg, bpr, (float*)d_out);
}

// Round 4
// 135.113 us; speedup vs baseline: 1.0640x; 1.0640x over previous
//
#include <hip/hip_runtime.h>
#include <stdint.h>

#define NN 15000
#define NE 60000

typedef unsigned short u16;
typedef __attribute__((ext_vector_type(8))) short short8;
typedef __attribute__((ext_vector_type(4))) float f32x4;

// workspace layout (bytes)
#define XF_OFF    0u
#define H_OFF     1920000u      // xf: 15000*64*2
#define W2T_OFF   9600000u      // h : 60000*64*2
#define ROOTT_OFF 10132480u     // w2t: 65*4096*2
#define WCATT_OFF 10140672u     // rootT: 64*64*2
#define SUMS_OFF  10171392u     // wcatT: 240*64*2 ; sums+cnt: 15000*65*4

__device__ __forceinline__ float b2f(u16 u) {
    union { unsigned i; float f; } v; v.i = ((unsigned)u) << 16; return v.f;
}
__device__ __forceinline__ unsigned cvtpk(float lo, float hi) {
    unsigned r;
    asm("v_cvt_pk_bf16_f32 %0, %1, %2" : "=v"(r) : "v"(lo), "v"(hi));
    return r;
}
__device__ __forceinline__ u16 f2b(float f) { return (u16)(cvtpk(f, f) & 0xffffu); }

// ---------------- kernel Z: zero sums+cnt ----------------
__global__ __launch_bounds__(256) void k_zero(float4* __restrict__ p, int n4) {
    int i = blockIdx.x * 256 + threadIdx.x;
    if (i < n4) p[i] = make_float4(0.f, 0.f, 0.f, 0.f);
}

// ---------------- kernel A: xf = bf16(concat(x, in_emb[inp], out_emb[outp])), x4 vec ----------------
__global__ __launch_bounds__(256) void k_xf(const float* __restrict__ x,
                                            const int* __restrict__ inp,
                                            const int* __restrict__ outp,
                                            const float* __restrict__ in_emb,
                                            const float* __restrict__ out_emb,
                                            u16* __restrict__ xf) {
    int tid = blockIdx.x * 256 + threadIdx.x;
    if (tid >= NN * 16) return;
    int n = tid >> 4, j4 = tid & 15;
    float4 v;
    if (j4 < 8)       v = *(const float4*)(x + n * 32 + j4 * 4);
    else if (j4 < 12) v = *(const float4*)(in_emb + inp[n] * 16 + (j4 - 8) * 4);
    else              v = *(const float4*)(out_emb + outp[n] * 16 + (j4 - 12) * 4);
    uint2 p;
    p.x = cvtpk(v.x, v.y);
    p.y = cvtpk(v.z, v.w);
    *(uint2*)(xf + n * 64 + j4 * 4) = p;
}

// ---------------- kernel T: weight re-layouts (f32 -> bf16) ----------------
// w2t[k][o][i] = w2[k][i*64+o] (k<64); w2t[64][o][i] = b2[i*64+o]
// rootT[c][i] = root_w[i][c];  wcatT[col][k] = Wcat[k][col]
__global__ __launch_bounds__(256) void k_prep(const float* __restrict__ w2,
                                              const float* __restrict__ b2,
                                              const float* __restrict__ rootw,
                                              const float* __restrict__ wsup,
                                              const float* __restrict__ wnt,
                                              const float* __restrict__ wtg,
                                              const float* __restrict__ wpr,
                                              u16* __restrict__ w2t,
                                              u16* __restrict__ rootT,
                                              u16* __restrict__ wcatT) {
    int idx = blockIdx.x * 256 + threadIdx.x;
    if (idx < 65 * 4096) {
        int k = idx >> 12, r = idx & 4095, o = r >> 6, i = r & 63;
        float v = (k < 64) ? w2[(k << 12) + (i << 6) + o] : b2[(i << 6) + o];
        w2t[idx] = f2b(v);
    } else if (idx < 65 * 4096 + 4096) {
        int t = idx - 65 * 4096; int c = t >> 6, i = t & 63;
        rootT[t] = f2b(rootw[i * 64 + c]);
    } else if (idx < 65 * 4096 + 4096 + 15360) {
        int t = idx - (65 * 4096 + 4096); int col = t >> 6, k = t & 63;
        float v;
        if (col < 16)       v = wsup[k * 16 + col];
        else if (col < 48)  v = wnt[k * 32 + col - 16];
        else if (col < 112) v = wtg[k * 64 + col - 48];
        else                v = wpr[k * 128 + col - 112];
        wcatT[t] = f2b(v);
    }
}

// ---------------- kernel B: h = bf16(relu(ea @ w1 + b1)); 128 edges/block ----------------
__global__ __launch_bounds__(256) void k_h(const int* __restrict__ ei,
                                           const int* __restrict__ ent,
                                           const int* __restrict__ enp,
                                           const float* __restrict__ esc,
                                           const float* __restrict__ nt_emb,
                                           const float* __restrict__ np_emb,
                                           const float* __restrict__ w1,
                                           const float* __restrict__ b1,
                                           u16* __restrict__ h,
                                           float* __restrict__ cnt) {
    __shared__ float w1f[33 * 64];
    __shared__ float b1f[64];
    __shared__ float ea[128][34];
    int tid = threadIdx.x;
    int e0 = blockIdx.x * 128;
    for (int i = tid; i < 33 * 64; i += 256) w1f[i] = w1[i];
    if (tid < 64) b1f[tid] = b1[tid];
    for (int idx = tid; idx < 128 * 33; idx += 256) {
        int le = idx / 33, f = idx - le * 33;
        int e = e0 + le;
        float v = 0.f;
        if (e < NE) {
            if (f < 16)      v = nt_emb[ent[e] * 16 + f];
            else if (f < 32) v = np_emb[enp[e] * 16 + (f - 16)];
            else             v = esc[e];
        }
        ea[le][f] = v;
    }
    if (tid < 128) {
        int e = e0 + tid;
        if (e < NE) atomicAdd(&cnt[ei[NE + e]], 1.0f);
    }
    __syncthreads();
    int c = tid & 63, eg = tid >> 6;
    for (int l = 0; l < 32; ++l) {
        int le = eg * 32 + l;
        int e = e0 + le;
        if (e >= NE) break;
        float acc = b1f[c];
        #pragma unroll
        for (int i = 0; i < 33; ++i) acc += ea[le][i] * w1f[i * 64 + c];
        h[(size_t)e * 64 + c] = f2b(fmaxf(acc, 0.f));
    }
}

// ---------------- kernel C: fused msg GEMM + scatter-add (q-scheme, pipelined) ----------------
// msg[e,o] = sum_k h[e,k]*q_k[e,o] + q_bias[e,o],  q_k[e,o] = sum_i g[e,i]*w2t[k][o][i]
// 128 edges/block, 512 threads = grp(2 k-halves) x qtr(4 x 32-edge). Wave: 2 strips x 16 edges.
// Single barrier/slice: double-buffered w2t LDS + 2-deep register prefetch.
__global__ __launch_bounds__(512) void k_msg(const int* __restrict__ ei,
                                             const u16* __restrict__ xf,
                                             const u16* __restrict__ hg,
                                             const u16* __restrict__ w2t,
                                             float* __restrict__ sums) {
    __shared__ __align__(16) char smem[49152];  // [0,16K): h tile swz; [16K,48K): w2t dbuf [2][2grp][8K]
    const int tid  = threadIdx.x;
    const int lane = tid & 63;
    const int wave = tid >> 6;
    const int grp  = wave >> 2;
    const int qtr  = wave & 3;
    const int lhi  = lane >> 4;
    const int llo  = lane & 15;
    const int e0   = blockIdx.x * 128;

    // stage h tile [128][64] bf16, XOR-swizzled (rows of 128B)
    #pragma unroll
    for (int it = 0; it < 2; ++it) {
        int seg = tid + it * 512;
        int row = seg >> 3, part = seg & 7;
        int e = e0 + row;
        uint4 v = make_uint4(0, 0, 0, 0);
        if (e < NE) v = *(const uint4*)(hg + (size_t)e * 64 + part * 8);
        int lin = row * 128 + part * 16;
        *(uint4*)(smem + (lin ^ ((row & 7) << 4))) = v;
    }

    // g fragments: raw bf16, loaded once (A-operand, never rebuilt)
    short8 a_raw[2][2];
    #pragma unroll
    for (int st = 0; st < 2; ++st) {
        int e = e0 + qtr * 32 + st * 16 + llo;
        int s = (e < NE) ? ei[e] : 0;
        #pragma unroll
        for (int c = 0; c < 2; ++c)
            a_raw[st][c] = *(const short8*)(xf + (size_t)s * 64 + c * 32 + lhi * 8);
    }

    // w2t slice prefetch pipeline. Slice schedule per step s: grp0 -> (s<32 ? s : 64); grp1 -> 32+s (dummy 64 at s=32)
    const int wlin  = tid * 16;
    const int wphys = wlin ^ (((wlin >> 7) & 7) << 4);
    uint4 v0 = *(const uint4*)((const char*)w2t + (size_t)0 * 8192 + wlin);
    uint4 v1 = *(const uint4*)((const char*)w2t + (size_t)32 * 8192 + wlin);
    *(uint4*)(smem + 16384 + wphys) = v0;
    *(uint4*)(smem + 16384 + 8192 + wphys) = v1;
    v0 = *(const uint4*)((const char*)w2t + (size_t)1 * 8192 + wlin);
    v1 = *(const uint4*)((const char*)w2t + (size_t)33 * 8192 + wlin);
    __syncthreads();

    f32x4 acc[2][4];
    #pragma unroll
    for (int st = 0; st < 2; ++st)
        #pragma unroll
        for (int o = 0; o < 4; ++o)
            acc[st][o] = (f32x4){0.f, 0.f, 0.f, 0.f};

    for (int s = 0; s < 33; ++s) {
        // write prefetched slice (for step s+1) into alternate buffer
        if (s + 1 < 33) {
            char* dst = smem + 16384 + ((s + 1) & 1) * 16384;
            *(uint4*)(dst + wphys) = v0;
            *(uint4*)(dst + 8192 + wphys) = v1;
        }
        // issue prefetch for step s+2
        if (s + 2 < 33) {
            int t0 = (s + 2 < 32) ? (s + 2) : 64;
            v0 = *(const uint4*)((const char*)w2t + (size_t)t0 * 8192 + wlin);
            v1 = *(const uint4*)((const char*)w2t + (size_t)(32 + s + 2) * 8192 + wlin);
        }
        // compute from buf[s&1]
        const char* wbase = smem + 16384 + (s & 1) * 16384 + grp * 8192;
        short8 bfr[2][4];
        #pragma unroll
        for (int c = 0; c < 2; ++c)
            #pragma unroll
            for (int o = 0; o < 4; ++o) {
                int loff = (o * 16 + llo) * 128 + c * 64 + lhi * 16;
                bfr[c][o] = *(const short8*)(wbase + (loff ^ ((llo & 7) << 4)));
            }
        if (grp == 0 || s < 32) {
            const bool bias = (grp == 0) && (s == 32);
            const int k = grp * 32 + s;
            #pragma unroll
            for (int st = 0; st < 2; ++st) {
                f32x4 q[4];
                #pragma unroll
                for (int o = 0; o < 4; ++o) {
                    q[o] = __builtin_amdgcn_mfma_f32_16x16x32_bf16(
                        a_raw[st][0], bfr[0][o], (f32x4){0.f, 0.f, 0.f, 0.f}, 0, 0, 0);
                    q[o] = __builtin_amdgcn_mfma_f32_16x16x32_bf16(
                        a_raw[st][1], bfr[1][o], q[o], 0, 0, 0);
                }
                #pragma unroll
                for (int r = 0; r < 4; ++r) {
                    float hf = 1.0f;
                    if (!bias) {
                        int erow = qtr * 32 + st * 16 + lhi * 4 + r;
                        hf = b2f(*(const u16*)(smem + ((erow * 128 + k * 2) ^ ((erow & 7) << 4))));
                    }
                    #pragma unroll
                    for (int o = 0; o < 4; ++o)
                        acc[st][o][r] += hf * q[o][r];
                }
            }
        }
        __syncthreads();
    }

    // scatter-add into sums[dst]: C/D layout col=lane&15, row=(lane>>4)*4+r
    #pragma unroll
    for (int st = 0; st < 2; ++st) {
        #pragma unroll
        for (int r = 0; r < 4; ++r) {
            int e = e0 + qtr * 32 + st * 16 + lhi * 4 + r;
            if (e < NE) {
                int d = ei[NE + e];
                float* base = sums + (size_t)d * 64;
                #pragma unroll
                for (int o = 0; o < 4; ++o)
                    atomicAdd(base + o * 16 + llo, acc[st][o][r]);
            }
        }
    }
}

// ---------------- kernel D: out = relu(aggr + xf@rootw + b); 4 heads (f32 out) ----------------
__global__ __launch_bounds__(256) void k_out(const u16* __restrict__ xf,
                                             const float* __restrict__ sums,
                                             const float* __restrict__ cnt,
                                             const u16* __restrict__ rootT,
                                             const u16* __restrict__ wcatT,
                                             const float* __restrict__ convb,
                                             const float* __restrict__ bsup,
                                             const float* __restrict__ bnt,
                                             const float* __restrict__ btg,
                                             const float* __restrict__ bpr,
                                             float* __restrict__ outp) {
    __shared__ __align__(16) u16 outlds[4][16][72];
    int tid = threadIdx.x;
    int wave = tid >> 6, lane = tid & 63;
    int lhi = lane >> 4, llo = lane & 15;
    int sid = blockIdx.x * 4 + wave;
    const bool live = (sid < 938);        // 938 = ceil(15000/16)
    if (!live) sid = 937;                 // clamp; keep all threads for barrier
    int n0 = sid * 16;

    short8 a1[2];
    #pragma unroll
    for (int c = 0; c < 2; ++c) {
        int node = n0 + llo; if (node >= NN) node = NN - 1;
        a1[c] = *(const short8*)(xf + (size_t)node * 64 + c * 32 + lhi * 8);
    }
    f32x4 racc[4];
    #pragma unroll
    for (int o = 0; o < 4; ++o) racc[o] = (f32x4){0.f, 0.f, 0.f, 0.f};
    #pragma unroll
    for (int c = 0; c < 2; ++c)
        #pragma unroll
        for (int o = 0; o < 4; ++o) {
            short8 b = *(const short8*)(rootT + (o * 16 + llo) * 64 + c * 32 + lhi * 8);
            racc[o] = __builtin_amdgcn_mfma_f32_16x16x32_bf16(a1[c], b, racc[o], 0, 0, 0);
        }
    #pragma unroll
    for (int o = 0; o < 4; ++o) {
        int col = o * 16 + llo;
        #pragma unroll
        for (int r = 0; r < 4; ++r) {
            int node = n0 + lhi * 4 + r;
            float v = 0.f;
            if (node < NN) v = sums[(size_t)node * 64 + col] / fmaxf(cnt[node], 1.0f);
            v += racc[o][r] + convb[col];
            v = fmaxf(v, 0.f);
            outlds[wave][lhi * 4 + r][col] = f2b(v);
        }
    }
    __syncthreads();
    short8 a2[2];
    #pragma unroll
    for (int c = 0; c < 2; ++c)
        a2[c] = *(const short8*)(&outlds[wave][llo][c * 32 + lhi * 8]);
    #pragma unroll
    for (int o = 0; o < 15; ++o) {
        f32x4 hacc = (f32x4){0.f, 0.f, 0.f, 0.f};
        #pragma unroll
        for (int c = 0; c < 2; ++c) {
            short8 b = *(const short8*)(wcatT + (o * 16 + llo) * 64 + c * 32 + lhi * 8);
            hacc = __builtin_amdgcn_mfma_f32_16x16x32_bf16(a2[c], b, hacc, 0, 0, 0);
        }
        int col = o * 16 + llo;
        float bv; size_t off0; int w_, csh;
        if (col < 16)       { bv = bsup[col];       off0 = 0;                 w_ = 16;  csh = 0;   }
        else if (col < 48)  { bv = bnt[col - 16];   off0 = (size_t)NN * 16;   w_ = 32;  csh = 16;  }
        else if (col < 112) { bv = btg[col - 48];   off0 = (size_t)NN * 48;   w_ = 64;  csh = 48;  }
        else                { bv = bpr[col - 112];  off0 = (size_t)NN * 112;  w_ = 128; csh = 112; }
        #pragma unroll
        for (int r = 0; r < 4; ++r) {
            int node = n0 + lhi * 4 + r;
            if (live && node < NN)
                outp[off0 + (size_t)node * w_ + (col - csh)] = hacc[r] + bv;
        }
    }
}

extern "C" void kernel_launch(void* const* d_in, const int* in_sizes, int n_in,
                              void* d_out, int out_size, void* d_ws, size_t ws_size,
                              hipStream_t stream) {
    const float* x        = (const float*)d_in[0];
    const int* input_np   = (const int*)d_in[1];
    const int* output_np  = (const int*)d_in[2];
    const int* edge_idx   = (const int*)d_in[3];
    const int* edge_nt    = (const int*)d_in[4];
    const int* edge_np    = (const int*)d_in[5];
    const float* edge_sc  = (const float*)d_in[6];
    const float* in_emb   = (const float*)d_in[7];
    const float* out_emb  = (const float*)d_in[8];
    const float* enp_emb  = (const float*)d_in[9];
    const float* ent_emb  = (const float*)d_in[10];
    const float* w1       = (const float*)d_in[11];
    const float* b1       = (const float*)d_in[12];
    const float* w2       = (const float*)d_in[13];
    const float* b2       = (const float*)d_in[14];
    const float* rootw    = (const float*)d_in[15];
    const float* convb    = (const float*)d_in[16];
    const float* wsup     = (const float*)d_in[17];
    const float* bsup     = (const float*)d_in[18];
    const float* wnt      = (const float*)d_in[19];
    const float* bnt      = (const float*)d_in[20];
    const float* wtg      = (const float*)d_in[21];
    const float* btg      = (const float*)d_in[22];
    const float* wpr      = (const float*)d_in[23];
    const float* bpr      = (const float*)d_in[24];

    char* ws = (char*)d_ws;
    u16* xf    = (u16*)(ws + XF_OFF);
    u16* hbuf  = (u16*)(ws + H_OFF);
    u16* w2t   = (u16*)(ws + W2T_OFF);
    u16* rootT = (u16*)(ws + ROOTT_OFF);
    u16* wcatT = (u16*)(ws + WCATT_OFF);
    float* sums = (float*)(ws + SUMS_OFF);
    float* cnt  = sums + (size_t)NN * 64;

    k_zero<<<953, 256, 0, stream>>>((float4*)sums, (NN * 65) / 4);
    k_prep<<<1116, 256, 0, stream>>>(w2, b2, rootw, wsup, wnt, wtg, wpr, w2t, rootT, wcatT);
    k_xf<<<938, 256, 0, stream>>>(x, input_np, output_np, in_emb, out_emb, xf);
    k_h<<<469, 256, 0, stream>>>(edge_idx, edge_nt, edge_np, edge_sc, ent_emb, enp_emb, w1, b1, hbuf, cnt);
    k_msg<<<469, 512, 0, stream>>>(edge_idx, xf, hbuf, w2t, sums);
    k_out<<<235, 256, 0, stream>>>(xf, sums, cnt, rootT, wcatT, convb, bsup, bnt, btg, bpr, (float*)d_out);
}